// Round 6
// baseline (368.075 us; speedup 1.0000x reference)
//
#include <hip/hip_runtime.h>

// SpecAdaConv2d via split-bf16 MFMA implicit GEMM.
// out[b,co,p] = sum_{ci,k} (alpha[b,ci]*w[co,ci,k]) * x[b,ci,p+shift(k)] + bias[co]
// fp32 -> (hi,lo) bf16 split on both w and x; 3 products hi*hi + hi*lo_x + lo_w*hi.
//
// R6 = R5 (XCD swizzle + T14 issue-early/write-late pipeline, 175us) with the
// LDS layout switched to the R2/R3-verified swizzled 128B row:
//   row px = 64 ushorts [32 hi | 32 lo], 16B slot s placed at s^(px&7).
// Effects: (a) LDS 49152->43520 B => 3 blocks/CU unambiguous (was ~2) ->
// 6 waves/SIMD; (b) read-side bank conflicts (7.67M cyc, on the ds_read->MFMA
// critical path) -> 0, as measured in R2/R3. Staging writes stay R1-style
// dwords (4-way conflicts measured latency-hidden/free); addr_lo = addr_hi^32
// still holds under the swizzle since (s|4)^m = (s^m)^4.

typedef __attribute__((ext_vector_type(8))) short short8;
typedef __attribute__((ext_vector_type(4))) float float4v;

#define BB 8
#define CI_N 64
#define CO_N 64
#define HH 256
#define WW 256
#define HW (HH * WW)
#define TW 32
#define TH 8
#define HALO_W 34
#define HALO_H 10
#define HALO_PX (HALO_W * HALO_H)   // 340

#define NFRAG (2 * 9 * 2 * 4 * 64 * 8)  // 73728 packed bf16 elems
#define SX_US (HALO_PX * 64)            // 21760 ushorts = 43520 B LDS

__device__ __forceinline__ unsigned f2bf(float v) {
    unsigned u = __float_as_uint(v);
    return (u + 0x7FFFu + ((u >> 16) & 1u)) >> 16;   // RNE to bf16
}

__global__ void prepack_w(const float* __restrict__ w, ushort* __restrict__ wp) {
    int idx = blockIdx.x * 256 + threadIdx.x;
    if (idx >= NFRAG) return;
    int j     = idx & 7;
    int lane  = (idx >> 3) & 63;
    int mt    = (idx >> 9) & 3;
    int plane = (idx >> 11) & 1;
    int rest  = idx >> 12;            // chunk*9 + k, 0..17
    int k     = rest % 9;
    int chunk = rest / 9;
    int co = mt * 16 + (lane & 15);
    int ci = chunk * 32 + (lane >> 4) * 8 + j;
    float v = w[(co * CI_N + ci) * 9 + k];
    unsigned hi = f2bf(v);
    float fhi = __uint_as_float(hi << 16);
    unsigned lo = f2bf(v - fhi);
    wp[idx] = (ushort)(plane ? lo : hi);
}

__global__ __launch_bounds__(512, 4) void conv_mfma(
    const float* __restrict__ x,      // (B, CIN, H, W)
    const float* __restrict__ alpha,  // (B, CIN)
    const ushort* __restrict__ wp,    // packed weights (d_ws)
    const float* __restrict__ bias,   // (COUT)
    float* __restrict__ out)          // (B, COUT, H, W)
{
    __shared__ __align__(16) ushort sx[SX_US];   // 43520 B -> 3 blocks/CU

    const int tid    = threadIdx.x;
    const int lane   = tid & 63;
    const int w_id   = tid >> 6;        // wave 0..7
    const int n_lane = lane & 15;
    const int q      = lane >> 4;

    // XCD-aware decode: id&7 pins one batch image per XCD (FETCH 217->96MB).
    const int id  = blockIdx.x;
    const int b   = id & 7;
    const int t   = id >> 3;            // 0..255
    const int tx  = t & 7;
    const int ty  = t >> 3;             // 0..31
    const int gx0 = tx * TW;
    const int gy0 = ty * TH;

    const int m_half = w_id >> 2;       // owns M-tiles m_half*2 + {0,1}
    const int n_q    = w_id & 3;        // owns N-tiles n_q*4 + {0..3}

    // acc init = bias (C/D layout: col=lane&15 -> px, row=q*4+r -> co)
    float4v acc[2][4];
#pragma unroll
    for (int mt = 0; mt < 2; ++mt) {
        float4v bi;
#pragma unroll
        for (int r = 0; r < 4; ++r)
            bi[r] = bias[(m_half * 2 + mt) * 16 + q * 4 + r];
#pragma unroll
        for (int nt = 0; nt < 4; ++nt) acc[mt][nt] = bi;
    }

    const float* xb = x + (size_t)b * CI_N * HW;

    // ---- staging geometry, computed once (shared by both chunks) ----
    int gofs[6];
    unsigned okm = 0;
#pragma unroll
    for (int it = 0; it < 6; ++it) {
        int hp = it * 64 + lane;
        int hy = hp / HALO_W;
        int hx = hp - hy * HALO_W;
        int gy = gy0 - 1 + hy;
        int gx = gx0 - 1 + hx;
        bool ok = (hp < HALO_PX) & ((unsigned)gy < HH) & ((unsigned)gx < WW);
        gofs[it] = ok ? gy * WW + gx : 0;   // clamped: load always valid
        okm |= (unsigned)ok << it;
    }
    const int cl = w_id * 4;   // this wave stages ci = chunk*32 + cl .. +3
    const int cs = cl >> 3;    // 16B slot index (0..3), same for cl..cl+3
    const int cw = cl & 7;     // within-slot ushort offset (0 or 4)
    float al0[4], al1[4];      // wave-uniform alphas per chunk
#pragma unroll
    for (int j = 0; j < 4; ++j) {
        al0[j] = alpha[b * CI_N + cl + j];
        al1[j] = alpha[b * CI_N + 32 + cl + j];
    }

    // raw staging loads for one chunk: r[j][it], ci = base+j
#define STAGE_LOAD(r, cbase)                                             \
    {                                                                    \
        _Pragma("unroll")                                                \
        for (int j = 0; j < 4; ++j) {                                    \
            const float* xp = xb + (size_t)((cbase) + cl + j) * HW;      \
            _Pragma("unroll")                                            \
            for (int it = 0; it < 6; ++it) r[j][it] = xp[gofs[it]];      \
        }                                                                \
    }

    // convert + swizzled-slot LDS write: hi dword at
    // hp*64 + ((cs^(hp&7))<<3) + cw (+2 for p2=1); lo at ^32.
#define STAGE_WRITE(r, al)                                               \
    {                                                                    \
        _Pragma("unroll")                                                \
        for (int it = 0; it < 6; ++it) {                                 \
            if (it < 5 || lane < 20) {  /* unit exists (hp<340) */       \
                const int hp = it * 64 + lane;                           \
                const int ah = hp * 64 + ((cs ^ (hp & 7)) << 3) + cw;    \
                const bool ok = (okm >> it) & 1;                         \
                float v[4];                                              \
                _Pragma("unroll")                                        \
                for (int j = 0; j < 4; ++j)                              \
                    v[j] = ok ? r[j][it] * al[j] : 0.0f;                 \
                _Pragma("unroll")                                        \
                for (int p2 = 0; p2 < 2; ++p2) {                         \
                    unsigned h0 = f2bf(v[2 * p2]);                       \
                    unsigned h1 = f2bf(v[2 * p2 + 1]);                   \
                    unsigned l0 = f2bf(v[2 * p2]                         \
                                       - __uint_as_float(h0 << 16));     \
                    unsigned l1 = f2bf(v[2 * p2 + 1]                     \
                                       - __uint_as_float(h1 << 16));     \
                    *(unsigned*)&sx[ah + 2 * p2]        = h0 | (h1 << 16); \
                    *(unsigned*)&sx[(ah + 2 * p2) ^ 32] = l0 | (l1 << 16); \
                }                                                        \
            }                                                            \
        }                                                                \
    }

    // compute phase for one chunk (reads sx + wp, accumulates)
#define COMPUTE(chunk)                                                   \
    {                                                                    \
        _Pragma("unroll")                                                \
        for (int k = 0; k < 9; ++k) {                                    \
            const int dy = k / 3 - 1;                                    \
            const int dx = k % 3 - 1;                                    \
            short8 a_hi[2], a_lo[2];                                     \
            _Pragma("unroll")                                            \
            for (int mt = 0; mt < 2; ++mt) {                             \
                int fh = (((chunk) * 9 + k) * 2 + 0) * 4 + (m_half * 2 + mt); \
                int fl = (((chunk) * 9 + k) * 2 + 1) * 4 + (m_half * 2 + mt); \
                a_hi[mt] = *(const short8*)(wp + (size_t)(fh * 64 + lane) * 8); \
                a_lo[mt] = *(const short8*)(wp + (size_t)(fl * 64 + lane) * 8); \
            }                                                            \
            _Pragma("unroll")                                            \
            for (int nt_i = 0; nt_i < 4; ++nt_i) {                       \
                const int prow = n_q * 2 + (nt_i >> 1) + 1 + dy;         \
                const int px = prow * HALO_W + 1 + (nt_i & 1) * 16 + dx + n_lane; \
                const int sw = (q ^ (px & 7)) << 3;                      \
                short8 b_hi = *(const short8*)&sx[px * 64 + sw];         \
                short8 b_lo = *(const short8*)&sx[px * 64 + (sw ^ 32)];  \
                acc[0][nt_i] = __builtin_amdgcn_mfma_f32_16x16x32_bf16(a_hi[0], b_hi, acc[0][nt_i], 0, 0, 0); \
                acc[1][nt_i] = __builtin_amdgcn_mfma_f32_16x16x32_bf16(a_hi[1], b_hi, acc[1][nt_i], 0, 0, 0); \
                acc[0][nt_i] = __builtin_amdgcn_mfma_f32_16x16x32_bf16(a_lo[0], b_hi, acc[0][nt_i], 0, 0, 0); \
                acc[1][nt_i] = __builtin_amdgcn_mfma_f32_16x16x32_bf16(a_lo[1], b_hi, acc[1][nt_i], 0, 0, 0); \
                acc[0][nt_i] = __builtin_amdgcn_mfma_f32_16x16x32_bf16(a_hi[0], b_lo, acc[0][nt_i], 0, 0, 0); \
                acc[1][nt_i] = __builtin_amdgcn_mfma_f32_16x16x32_bf16(a_hi[1], b_lo, acc[1][nt_i], 0, 0, 0); \
            }                                                            \
        }                                                                \
    }

    // ---- pipelined schedule (T14) ----
    float r0[4][6], r1[4][6];
    STAGE_LOAD(r0, 0);          // chunk0 loads
    STAGE_WRITE(r0, al0);       // convert + LDS write
    __syncthreads();

    STAGE_LOAD(r1, 32);         // chunk1 loads issued EARLY (hide under MFMA)
    COMPUTE(0);
    __syncthreads();            // all sx reads of chunk0 done

    STAGE_WRITE(r1, al1);       // vmcnt drained here, not before compute
    __syncthreads();

    COMPUTE(1);

    // ---- epilogue: store (64B-segment coalescing: 16 px x 4 co groups) ----
#pragma unroll
    for (int mt = 0; mt < 2; ++mt) {
        const int m0 = (m_half * 2 + mt) * 16;
#pragma unroll
        for (int nt_i = 0; nt_i < 4; ++nt_i) {
            const int nt = n_q * 4 + nt_i;
            const int gy = gy0 + (nt >> 1);
            const int gx = gx0 + (nt & 1) * 16 + n_lane;
#pragma unroll
            for (int r = 0; r < 4; ++r) {
                const int co = m0 + q * 4 + r;
                out[(((size_t)b * CO_N + co) * HH + gy) * WW + gx] = acc[mt][nt_i][r];
            }
        }
    }
#undef STAGE_LOAD
#undef STAGE_WRITE
#undef COMPUTE
}

extern "C" void kernel_launch(void* const* d_in, const int* in_sizes, int n_in,
                              void* d_out, int out_size, void* d_ws, size_t ws_size,
                              hipStream_t stream) {
    const float* x     = (const float*)d_in[0];
    const float* alpha = (const float*)d_in[1];
    const float* w     = (const float*)d_in[2];
    const float* bias  = (const float*)d_in[3];
    float* out  = (float*)d_out;
    ushort* wpk = (ushort*)d_ws;

    prepack_w<<<dim3((NFRAG + 255) / 256), dim3(256), 0, stream>>>(w, wpk);

    // 1-D grid so the in-kernel XCD decode controls locality (2048 blocks)
    conv_mfma<<<dim3(2048), dim3(512), 0, stream>>>(x, alpha, wpk, bias, out);
}